// Round 6
// baseline (676.617 us; speedup 1.0000x reference)
//
#include <hip/hip_runtime.h>

#define TT 512

typedef __attribute__((ext_vector_type(8))) short bf16x8;
typedef __attribute__((ext_vector_type(4))) short s16x4;
typedef __attribute__((ext_vector_type(4))) float f32x4;

__device__ inline short f2bf(float f) {
    // round-to-nearest-even fp32 -> bf16 (values bounded; no NaN path needed)
    unsigned u = __float_as_uint(f);
    u += 0x7FFFu + ((u >> 16) & 1u);
    return (short)(u >> 16);
}

#define MFMA16(a, b, c) __builtin_amdgcn_mfma_f32_16x16x32_bf16((a), (b), (c), 0, 0, 0)

// 192 threads = 3 waves = 1 wave PER LAYER. WG owns 4 batch rows for all T;
// grid = 256 = 1 WG/CU. Each wave computes ALL 192 gate-cols of its layer
// (12 C-tiles, 48 MFMAs/step) -> NO sibling waves, so h(t-1) never crosses
// a barrier: the wave writes h(t) then reads back its next A-frags
// intra-wave (per-wave DS ordering). hh-MFMAs for step t issue BEFORE the
// barrier; only the cross-layer input read is barrier-gated. 3-wave barrier
// per step. LDS traffic: 24 DS instrs/step vs 60 in the 12-wave design.
// A-frag rows replicated 4x (A row r = batch row r>>2): lane (q,n_) C reg 0
// = (batchrow q, col n_) preactivation for each tile. Weights resident:
// 48 B-frags = 192 VGPRs (1 wave/SIMD, ~310 VGPR total, no spill < 450).
// Gate transcendentals via exp2: r/z weights+biases pre-scaled by -log2e,
// n-gate by 2*log2e at frag build (R5-verified numerics).
__global__ __launch_bounds__(192, 1)
void gru_fused(const float* __restrict__ x,
               const float* __restrict__ Wih0, const float* __restrict__ Whh0,
               const float* __restrict__ bih0, const float* __restrict__ bhh0,
               const float* __restrict__ Wih1, const float* __restrict__ Whh1,
               const float* __restrict__ bih1, const float* __restrict__ bhh1,
               const float* __restrict__ Wih2, const float* __restrict__ Whh2,
               const float* __restrict__ bih2, const float* __restrict__ bhh2,
               const float* __restrict__ fc1w, const float* __restrict__ fc1b,
               const float* __restrict__ fc2w, const float* __restrict__ fc2b,
               float* __restrict__ out)
{
    // x as bf16: [t][row][16], unpadded (64 KiB). Layer-0 A-frags exec-masked q<2.
    __shared__ __align__(16) short xls[TT][4][16];
    // h double buffers: row stride 80 shorts (16B-aligned granules; reads 2-way
    // broadcast-free, b16 writes exactly 2 lanes/bank).
    __shared__ __align__(16) short hbuf[3][2][4 * 80];
    __shared__ float h2out[4][64];
    __shared__ float fcz[4][32];

    const int tid = threadIdx.x;
    const int l   = tid & 63;
    const int wid = tid >> 6;                       // 0..2
    const int Ls  = __builtin_amdgcn_readfirstlane(wid);  // layer (scalar)
    const int n_  = l & 15;                         // A/C col | B col
    const int q   = l >> 4;                         // quad (k-slice / batch row)
    const int ar  = n_ >> 2;                        // replicated A row -> batch row
    const int rbase = blockIdx.x * 4;

    // ---- LDS init: hbuf = 0 (h(-1)=0) ----
    for (int i = tid; i < 3 * 2 * 320; i += 192) (&hbuf[0][0][0])[i] = 0;

    // ---- stage all x for this WG's 4 rows (float4 loads -> bf16 LDS) ----
    {
        const float4* xv = (const float4*)(x + (size_t)rbase * (TT * 16));
        for (int i = tid; i < 8192; i += 192) {
            float4 v = xv[i];
            const int row = i >> 11, rem = i & 2047;    // 2048 float4 per row
            s16x4 pv = { f2bf(v.x), f2bf(v.y), f2bf(v.z), f2bf(v.w) };
            *(s16x4*)&xls[rem >> 2][row][(rem & 3) * 4] = pv;
        }
    }

    // ---- per-wave weight selection ----
    const float* Wih = (Ls == 0) ? Wih0 : (Ls == 1) ? Wih1 : Wih2;
    const float* Whh = (Ls == 0) ? Whh0 : (Ls == 1) ? Whh1 : Whh2;
    const float* bih = (Ls == 0) ? bih0 : (Ls == 1) ? bih1 : bih2;
    const float* bhh = (Ls == 0) ? bhh0 : (Ls == 1) ? bhh1 : bhh2;
    const int ldih = (Ls == 0) ? 16 : 64;   // W_ih0 is [192,16]; K zero-padded

    const float L2E = 1.44269504088896f;

    // ---- resident B-frags: 12 tiles (cols ti*16..ti*16+15), 2 K-halves ----
    // tiles 0-3 = r gate, 4-7 = z, 8-11 = n. B-frag: col = n_, k = kt*32+q*8+j.
    bf16x8 wihf[12][2], whhf[12][2];
#pragma unroll
    for (int ti = 0; ti < 12; ++ti) {
        const int gc = ti * 16;
        const float sc = (ti < 8) ? -L2E : 2.0f * L2E;
#pragma unroll
        for (int kt = 0; kt < 2; ++kt) {
            const int kb = kt * 32 + q * 8;
            bf16x8 fi, fh;
#pragma unroll
            for (int j = 0; j < 8; ++j) {
                const int k = kb + j;
                float vi = (k < ldih) ? Wih[(gc + n_) * ldih + k] : 0.0f;
                float vh = Whh[(gc + n_) * 64 + k];
                fi[j] = f2bf(vi * sc);
                fh[j] = f2bf(vh * sc);
            }
            wihf[ti][kt] = fi;
            whhf[ti][kt] = fh;
        }
    }

    // ---- per-lane scalar biases for its 4 units u_k = k*16 + n_ ----
    float br_[4], bz_[4], bxn_[4], bhn_[4];
#pragma unroll
    for (int k = 0; k < 4; ++k) {
        const int c = k * 16 + n_;
        br_[k]  = -L2E * (bih[c] + bhh[c]);
        bz_[k]  = -L2E * (bih[64 + c] + bhh[64 + c]);
        bxn_[k] = 2.0f * L2E * bih[128 + c];
        bhn_[k] = 2.0f * L2E * bhh[128 + c];
    }

    const f32x4 zf4 = {0.f, 0.f, 0.f, 0.f};
    const bf16x8 zero8 = {0,0,0,0,0,0,0,0};
    bf16x8 hA0 = zero8, hA1 = zero8;   // h(-1) = 0, carried in regs
    float hp[4] = {0.f, 0.f, 0.f, 0.f};

    __syncthreads();

    // ---- pipelined time loop: wave of layer L processes t = s - L ----
    // x2 unroll so buffer parity is per-copy constant.
#define GRU_STEP(sv, par)                                                        \
    {                                                                            \
        const int tw = (sv) - Ls;                                                \
        if (tw >= 0 && tw < TT) {                                                \
            const int bi = (par) ^ (Ls & 1);                                     \
            /* cross-layer input read (barrier-gated data) issued first */       \
            bf16x8 iA0 = zero8, iA1 = zero8;                                     \
            if (Ls == 0) {                                                       \
                if (q < 2) iA0 = *(const bf16x8*)(&xls[tw][ar][q * 8]);          \
            } else {                                                             \
                const short* inp = &hbuf[Ls - 1][bi][0];                         \
                iA0 = *(const bf16x8*)(inp + ar * 80 + q * 8);                   \
                iA1 = *(const bf16x8*)(inp + ar * 80 + 32 + q * 8);              \
            }                                                                    \
            /* hh MFMAs use hA already in regs -> overlap iA latency */          \
            f32x4 accr[4], accz[4], cin[4], chn_[4];                             \
            _Pragma("unroll")                                                    \
            for (int k = 0; k < 4; ++k) {                                        \
                accr[k] = MFMA16(hA0, whhf[k][0], zf4);                          \
                accr[k] = MFMA16(hA1, whhf[k][1], accr[k]);                      \
                accz[k] = MFMA16(hA0, whhf[4 + k][0], zf4);                      \
                accz[k] = MFMA16(hA1, whhf[4 + k][1], accz[k]);                  \
                chn_[k] = MFMA16(hA0, whhf[8 + k][0], zf4);                      \
                chn_[k] = MFMA16(hA1, whhf[8 + k][1], chn_[k]);                  \
            }                                                                    \
            _Pragma("unroll")                                                    \
            for (int k = 0; k < 4; ++k) {                                        \
                accr[k] = MFMA16(iA0, wihf[k][0], accr[k]);                      \
                accr[k] = MFMA16(iA1, wihf[k][1], accr[k]);                      \
                accz[k] = MFMA16(iA0, wihf[4 + k][0], accz[k]);                  \
                accz[k] = MFMA16(iA1, wihf[4 + k][1], accz[k]);                  \
                cin[k]  = MFMA16(iA0, wihf[8 + k][0], zf4);                      \
                cin[k]  = MFMA16(iA1, wihf[8 + k][1], cin[k]);                   \
            }                                                                    \
            /* gate math: 4 units per lane (unit k*16+n_, batch row q) */        \
            float hv_[4];                                                        \
            _Pragma("unroll")                                                    \
            for (int k = 0; k < 4; ++k) {                                        \
                const float pr = accr[k][0] + br_[k];                            \
                const float pz = accz[k][0] + bz_[k];                            \
                const float rr = __fdividef(1.0f, 1.0f + exp2f(pr));             \
                const float zz = __fdividef(1.0f, 1.0f + exp2f(pz));             \
                const float sn = (cin[k][0] + bxn_[k]) + rr * (chn_[k][0] + bhn_[k]); \
                const float nn = 1.0f - __fdividef(2.0f, 1.0f + exp2f(sn));      \
                const float hv = nn + zz * (hp[k] - nn);                         \
                hp[k] = hv; hv_[k] = hv;                                         \
            }                                                                    \
            /* write h(t), then intra-wave readback of next step's A-frags */    \
            short* ob = &hbuf[Ls][bi][0];                                        \
            _Pragma("unroll")                                                    \
            for (int k = 0; k < 4; ++k) ob[q * 80 + k * 16 + n_] = f2bf(hv_[k]); \
            hA0 = *(const bf16x8*)(ob + ar * 80 + q * 8);                        \
            hA1 = *(const bf16x8*)(ob + ar * 80 + 32 + q * 8);                   \
        }                                                                        \
        __syncthreads();                                                         \
    }

    for (int s0 = 0; s0 < TT + 2; s0 += 2) {
        GRU_STEP(s0, 0)
        GRU_STEP(s0 + 1, 1)
    }
#undef GRU_STEP

    // ---- FC head: layer-2 wave holds h2(T-1), 4 values per lane ----
    if (wid == 2) {
#pragma unroll
        for (int k = 0; k < 4; ++k) h2out[q][k * 16 + n_] = hp[k];
    }
    __syncthreads();
    if (tid < 128) {
        const int row = tid >> 5, uu = tid & 31;
        float acc = fc1b[uu];
#pragma unroll
        for (int k = 0; k < 64; ++k) acc += h2out[row][k] * fc1w[uu * 64 + k];
        fcz[row][uu] = fmaxf(acc, 0.0f);
    }
    __syncthreads();
    if (tid < 4) {
        float y = fc2b[0];
#pragma unroll
        for (int uu = 0; uu < 32; ++uu) y += fcz[tid][uu] * fc2w[uu];
        out[rbase + tid] = y;
    }
}

extern "C" void kernel_launch(void* const* d_in, const int* in_sizes, int n_in,
                              void* d_out, int out_size, void* d_ws, size_t ws_size,
                              hipStream_t stream) {
    (void)in_sizes; (void)n_in; (void)d_ws; (void)ws_size; (void)out_size;
    gru_fused<<<dim3(256), dim3(192), 0, stream>>>(
        (const float*)d_in[0],
        (const float*)d_in[1],  (const float*)d_in[2],  (const float*)d_in[3],  (const float*)d_in[4],
        (const float*)d_in[5],  (const float*)d_in[6],  (const float*)d_in[7],  (const float*)d_in[8],
        (const float*)d_in[9],  (const float*)d_in[10], (const float*)d_in[11], (const float*)d_in[12],
        (const float*)d_in[13], (const float*)d_in[14], (const float*)d_in[15], (const float*)d_in[16],
        (float*)d_out);
}